// Round 5
// baseline (1594.926 us; speedup 1.0000x reference)
//
#include <hip/hip_runtime.h>

#define NV 50000
#define NE 5000
#define NC 16
#define TAU_INV 2.0f
#define EPS 1e-8f

#define NCH 100          // v-chunks (part partial scheme unchanged)
#define VCH 500          // rows per chunk
#define NSUB 5           // sub-chunks per chunk (one scan block each)
#define SUBV 100         // rows per sub-chunk
#define CAP 64           // list slots per (edge, sub-chunk); Binom(100,0.02) mean 2 -> safe
#define NEP 5120         // padded edge stride for cnt/list arrays
#define EPL 2            // edges per lane in gather
#define NXB 10           // gather x-blocks: 10*256*2 = 5120 slots >= 5000
#define NLANE 5120

typedef float vf4 __attribute__((ext_vector_type(4)));
typedef float vf2 __attribute__((ext_vector_type(2)));

// ---------------- softmax: one thread per row, both pred_s and pred_t.
// Output layout: p[v][32] = [softmax(pred_s[v]) (16) | softmax(pred_t[v]) (16)]
__global__ __launch_bounds__(256) void softmax_kernel(
    const float* __restrict__ pred_s, const float* __restrict__ pred_t,
    float* __restrict__ p) {
  int i = blockIdx.x * 256 + threadIdx.x;
  if (i >= 2 * NV) return;
  const float* src;
  float* dst;
  if (i < NV) { src = pred_s + (size_t)i * NC; dst = p + (size_t)i * 32; }
  else        { int j = i - NV; src = pred_t + (size_t)j * NC; dst = p + (size_t)j * 32 + 16; }
  float4 a = ((const float4*)src)[0];
  float4 b = ((const float4*)src)[1];
  float4 c = ((const float4*)src)[2];
  float4 d = ((const float4*)src)[3];
  float x[16] = {a.x,a.y,a.z,a.w, b.x,b.y,b.z,b.w, c.x,c.y,c.z,c.w, d.x,d.y,d.z,d.w};
  float mx = x[0];
#pragma unroll
  for (int k = 1; k < 16; ++k) mx = fmaxf(mx, x[k]);
  float sum = 0.f;
#pragma unroll
  for (int k = 0; k < 16; ++k) { x[k] = expf(x[k] - mx); sum += x[k]; }
  float inv = 1.f / sum;
#pragma unroll
  for (int k = 0; k < 16; ++k) x[k] *= inv;
  float4 o0 = {x[0], x[1], x[2], x[3]};
  float4 o1 = {x[4], x[5], x[6], x[7]};
  float4 o2 = {x[8], x[9], x[10], x[11]};
  float4 o3 = {x[12], x[13], x[14], x[15]};
  ((float4*)dst)[0] = o0;
  ((float4*)dst)[1] = o1;
  ((float4*)dst)[2] = o2;
  ((float4*)dst)[3] = o3;
}

// ---------------- scan: H (binary) -> per-(edge, sub-chunk) vertex lists.
// Block b = y*NSUB+q owns rows [y*500 + q*100, +100) x ALL 5000 edges: the H read
// is a pure contiguous 20KB-per-row stream (copy pattern). Lane t owns vf4 slots
// {s*256+t | s<5, idx<1250} -> 20 fixed edges, so each edge's appends come from
// ONE thread in row-ascending order (list order = v order, exact float-sum order).
__global__ __launch_bounds__(256) void scan_kernel(
    const float* __restrict__ H, unsigned short* __restrict__ lists,
    unsigned int* __restrict__ cnt) {
  int b = blockIdx.x;               // 0..499
  int y = b / NSUB, q = b - y * NSUB;
  int v0 = y * VCH + q * SUBV;
  int t = threadIdx.x;
  bool last = (t < 1250 - 1024);    // slot s=4 valid for t<226

  unsigned int cs[5][4];
#pragma unroll
  for (int s = 0; s < 5; ++s)
#pragma unroll
    for (int c = 0; c < 4; ++c) cs[s][c] = 0;

  size_t listBase = (size_t)b * CAP * NEP;

  for (int r = 0; r < SUBV; ++r) {
    const float* __restrict__ row = H + (size_t)(v0 + r) * NE;
    unsigned short vl = (unsigned short)(q * SUBV + r);   // v-local within chunk
#pragma unroll
    for (int s = 0; s < 5; ++s) {
      if (s < 4 || last) {
        int idx = s * 256 + t;
        vf4 x = __builtin_nontemporal_load((const vf4*)(row + (size_t)idx * 4));
        int e = idx * 4;
        if (x.x != 0.f) { lists[listBase + (size_t)cs[s][0] * NEP + e + 0] = vl; cs[s][0]++; }
        if (x.y != 0.f) { lists[listBase + (size_t)cs[s][1] * NEP + e + 1] = vl; cs[s][1]++; }
        if (x.z != 0.f) { lists[listBase + (size_t)cs[s][2] * NEP + e + 2] = vl; cs[s][2]++; }
        if (x.w != 0.f) { lists[listBase + (size_t)cs[s][3] * NEP + e + 3] = vl; cs[s][3]++; }
      }
    }
  }
#pragma unroll
  for (int s = 0; s < 5; ++s) {
    if (s < 4 || last) {
      int idx = s * 256 + t;
      uint4 w = {cs[s][0], cs[s][1], cs[s][2], cs[s][3]};
      *(uint4*)(cnt + (size_t)b * NEP + (size_t)idx * 4) = w;   // 16B-aligned
    }
  }
}

// ---------------- gather: sparse accumulation. Block (y, xb): stages p-chunk in
// LDS (XOR-swizzled rows: elem c stored at c^(v&31) -> bank (v+c)%32, gathers
// conflict-free), then per edge walks its q=0..4 lists in v-ascending order.
// Adds are bitwise-identical to the dense fmaf chain (H is exactly 0/1).
// part layout: part[y][k][NLANE], k: 0..15 S, 16..31 T, 32 deg
__global__ __launch_bounds__(256) void gather_kernel(
    const unsigned short* __restrict__ lists, const unsigned int* __restrict__ cnt,
    const float* __restrict__ p, float* __restrict__ part) {
  __shared__ float lp[VCH * 32];   // 64,000 B
  int b = blockIdx.x;
  int item = (b & 7) * 125 + (b >> 3);   // 1000 = 8*125: bijective XCD swizzle
  int xb = item % NXB;
  int y  = item / NXB;
  int e0 = EPL * (xb * 256 + (int)threadIdx.x);
  if (e0 > NE - EPL) e0 = NE - EPL;   // dup lanes compute identical values: benign
  int v0 = y * VCH;

  {
    const float* __restrict__ src = p + (size_t)v0 * 32;
    for (int i = threadIdx.x; i < VCH * 32; i += 256) {
      int v = i >> 5, c = i & 31;
      lp[(v << 5) + (c ^ (v & 31))] = src[i];
    }
  }
  __syncthreads();

  float aS0[16], aT0[16], aS1[16], aT1[16];
#pragma unroll
  for (int k = 0; k < 16; ++k) { aS0[k] = 0.f; aT0[k] = 0.f; aS1[k] = 0.f; aT1[k] = 0.f; }
  float deg0 = 0.f, deg1 = 0.f;

#define EDGE_ACC(AS, AT, DEG, K)                                          \
  {                                                                       \
    int e = e0 + K;                                                       \
    for (int q = 0; q < NSUB; ++q) {                                      \
      int sb = y * NSUB + q;                                              \
      unsigned int c = cnt[(size_t)sb * NEP + e];                         \
      DEG += (float)c;                                                    \
      const unsigned short* __restrict__ lb =                             \
          lists + (size_t)sb * CAP * NEP + e;                             \
      for (unsigned int j = 0; j < c; ++j) {                              \
        int v = (int)lb[(size_t)j * NEP];                                 \
        int sw = v & 31;                                                  \
        const float* __restrict__ rp = lp + (v << 5);                     \
        _Pragma("unroll")                                                 \
        for (int cc = 0; cc < 16; ++cc) AS[cc] += rp[cc ^ sw];            \
        _Pragma("unroll")                                                 \
        for (int cc = 0; cc < 16; ++cc) AT[cc] += rp[(16 + cc) ^ sw];     \
      }                                                                   \
    }                                                                     \
  }

  EDGE_ACC(aS0, aT0, deg0, 0)
  EDGE_ACC(aS1, aT1, deg1, 1)
#undef EDGE_ACC

  float* op = part + (size_t)y * 33 * NLANE + e0;
#pragma unroll
  for (int k = 0; k < 16; ++k) {
    vf2 w = {aS0[k], aS1[k]};
    *(vf2*)(op + (size_t)k * NLANE) = w;
  }
#pragma unroll
  for (int k = 0; k < 16; ++k) {
    vf2 w = {aT0[k], aT1[k]};
    *(vf2*)(op + (size_t)(16 + k) * NLANE) = w;
  }
  { vf2 w = {deg0, deg1}; *(vf2*)(op + (size_t)32 * NLANE) = w; }
}

// ---------------- reduce the NCH partials: acc[k][NLANE] = sum_y part[y][k][NLANE]
__global__ __launch_bounds__(256) void reduce_kernel(
    const float* __restrict__ part, float* __restrict__ acc) {
  int i = blockIdx.x * 256 + threadIdx.x;
  if (i >= 33 * NLANE) return;
  float s = 0.f;
#pragma unroll 4
  for (int y = 0; y < NCH; ++y)
    s += part[(size_t)y * 33 * NLANE + i];
  acc[i] = s;
}

// ---------------- per-edge KL + masked reduction (single block, 256 threads)
// acc layout: acc[k*NLANE + e]; S at k, T at 16+k, deg at 32
__global__ __launch_bounds__(256) void kl_kernel(
    const float* __restrict__ acc, const unsigned char* __restrict__ e_mask,
    float* __restrict__ out) {
  __shared__ float snum[4];
  __shared__ float scnt[4];
  int t = threadIdx.x;
  float num = 0.f, cnt = 0.f;
  for (int e = t; e < NE; e += 256) {
    if (e_mask[e]) {
      float deg = acc[(size_t)32 * NLANE + e];
      float invd = 1.f / deg;
      float kl = 0.f;
#pragma unroll
      for (int k = 0; k < 16; ++k) {
        float ms = acc[(size_t)k * NLANE + e] * invd;
        float mt = acc[(size_t)(16 + k) * NLANE + e] * invd;
        float xs = ms * TAU_INV + EPS;
        float xt = mt * TAU_INV + EPS;
        kl += xt * (logf(xt) - logf(xs));
      }
      num += kl;
      cnt += 1.f;
    }
  }
#pragma unroll
  for (int off = 32; off > 0; off >>= 1) {
    num += __shfl_down(num, off, 64);
    cnt += __shfl_down(cnt, off, 64);
  }
  if ((t & 63) == 0) { snum[t >> 6] = num; scnt[t >> 6] = cnt; }
  __syncthreads();
  if (t == 0) {
    float n = snum[0] + snum[1] + snum[2] + snum[3];
    float c2 = scnt[0] + scnt[1] + scnt[2] + scnt[3];
    out[0] = n / fmaxf(c2, 1.f);
  }
}

extern "C" void kernel_launch(void* const* d_in, const int* in_sizes, int n_in,
                              void* d_out, int out_size, void* d_ws, size_t ws_size,
                              hipStream_t stream) {
  const float* pred_s = (const float*)d_in[0];
  const float* pred_t = (const float*)d_in[1];
  const float* H      = (const float*)d_in[2];
  const unsigned char* e_mask = (const unsigned char*)d_in[3];

  float* ws   = (float*)d_ws;
  float* p    = ws;                                    // NV*32          (6.40 MB)
  float* acc  = p + (size_t)NV * 32;                   // 33*NLANE       (0.68 MB)
  float* part = acc + (size_t)33 * NLANE;              // NCH*33*NLANE   (67.6 MB)
  unsigned int* cnt = (unsigned int*)(part + (size_t)NCH * 33 * NLANE);  // 500*NEP u32 (10.2 MB)
  unsigned short* lists = (unsigned short*)(cnt + (size_t)NCH * NSUB * NEP); // 500*CAP*NEP u16 (328 MB)

  softmax_kernel<<<dim3((2 * NV + 255) / 256), 256, 0, stream>>>(pred_s, pred_t, p);
  scan_kernel<<<dim3(NCH * NSUB), 256, 0, stream>>>(H, lists, cnt);
  gather_kernel<<<dim3(NCH * NXB), 256, 0, stream>>>(lists, cnt, p, part);
  reduce_kernel<<<dim3((33 * NLANE + 255) / 256), 256, 0, stream>>>(part, acc);
  kl_kernel<<<1, 256, 0, stream>>>(acc, e_mask, (float*)d_out);
}

// Round 6
// 1343.231 us; speedup vs baseline: 1.1874x; 1.1874x over previous
//
#include <hip/hip_runtime.h>

#define NV 50000
#define NE 5000
#define NC 16
#define TAU_INV 2.0f
#define EPS 1e-8f

#define NCH 100         // v-chunks (part round-trip 67.6 MB)
#define VCH 500         // NV / NCH ; LDS slice = 500*32*4 = 62.5 KB (< 64 KB static)
#define GRP 2           // h-load ring depth (500 % 2 == 0) -- R0-proven
#define NXB 5           // x-blocks; 5 * 256 lanes * 4 edges = 5120 slots >= 5000
#define NBLK (NXB * NCH)   // 500
#define NLANE 5120
#define FB 80           // finale blocks: NLANE / 64

typedef float vf4 __attribute__((ext_vector_type(4)));

// ---------------- softmax: one thread per row, both pred_s and pred_t.
// Output layout: p[v][32] = [softmax(pred_s[v]) (16) | softmax(pred_t[v]) (16)]
// Thread (0,0) also zeroes the finale's 3 scalars (stream-ordered before finale).
__global__ __launch_bounds__(256) void softmax_kernel(
    const float* __restrict__ pred_s, const float* __restrict__ pred_t,
    float* __restrict__ p, float* __restrict__ scal) {
  int i = blockIdx.x * 256 + threadIdx.x;
  if (i == 0) { scal[0] = 0.f; scal[1] = 0.f; scal[2] = 0.f; }  // num, cnt, ticket
  if (i >= 2 * NV) return;
  const float* src;
  float* dst;
  if (i < NV) { src = pred_s + (size_t)i * NC; dst = p + (size_t)i * 32; }
  else        { int j = i - NV; src = pred_t + (size_t)j * NC; dst = p + (size_t)j * 32 + 16; }
  float4 a = ((const float4*)src)[0];
  float4 b = ((const float4*)src)[1];
  float4 c = ((const float4*)src)[2];
  float4 d = ((const float4*)src)[3];
  float x[16] = {a.x,a.y,a.z,a.w, b.x,b.y,b.z,b.w, c.x,c.y,c.z,c.w, d.x,d.y,d.z,d.w};
  float mx = x[0];
#pragma unroll
  for (int k = 1; k < 16; ++k) mx = fmaxf(mx, x[k]);
  float sum = 0.f;
#pragma unroll
  for (int k = 0; k < 16; ++k) { x[k] = expf(x[k] - mx); sum += x[k]; }
  float inv = 1.f / sum;
#pragma unroll
  for (int k = 0; k < 16; ++k) x[k] *= inv;
  float4 o0 = {x[0], x[1], x[2], x[3]};
  float4 o1 = {x[4], x[5], x[6], x[7]};
  float4 o2 = {x[8], x[9], x[10], x[11]};
  float4 o3 = {x[12], x[13], x[14], x[15]};
  ((float4*)dst)[0] = o0;
  ((float4*)dst)[1] = o1;
  ((float4*)dst)[2] = o2;
  ((float4*)dst)[3] = o3;
}

// ---------------- main accumulation (R0-proven structure), 4 edges per lane,
// nontemporal H stream, XCD-slab swizzle. Part stores are NORMAL (L3-resident
// for finale). part layout: part[y][k][NLANE], k: 0..15 S, 16..31 T, 32 deg
__global__ __launch_bounds__(256) void accum_kernel(
    const float* __restrict__ H, const float* __restrict__ p,
    float* __restrict__ part) {
  __shared__ float lp[VCH * 32];   // 62.5 KB
  int b = blockIdx.x;
  // NBLK=500: blocks 0..495 swizzle bijectively (8 XCD slabs of 62), rest identity
  int item;
  if (b < 496) item = (b & 7) * 62 + (b >> 3);
  else         item = b;
  int xb = item % NXB;
  int y  = item / NXB;
  int e0 = 4 * (xb * 256 + (int)threadIdx.x);
  if (e0 > NE - 4) e0 = NE - 4;   // dup lanes write identical values: benign
  int v0 = y * VCH;

  // stage the p slice (contiguous 64 KB) into LDS, coalesced float4
  {
    const float4* __restrict__ src = (const float4*)(p + (size_t)v0 * 32);
    float4* dst = (float4*)lp;
    for (int i = threadIdx.x; i < VCH * 8; i += 256) dst[i] = src[i];
  }
  __syncthreads();

  float4 aS[16], aT[16], dg;
#pragma unroll
  for (int k = 0; k < 16; ++k) {
    aS[k] = make_float4(0.f, 0.f, 0.f, 0.f);
    aT[k] = make_float4(0.f, 0.f, 0.f, 0.f);
  }
  dg = make_float4(0.f, 0.f, 0.f, 0.f);

  const float* __restrict__ hp = H + (size_t)v0 * NE + e0;

  vf4 hc[GRP];
#pragma unroll
  for (int u = 0; u < GRP; ++u)
    hc[u] = __builtin_nontemporal_load((const vf4*)(hp + (size_t)u * NE));

  for (int vb = 0; vb < VCH; vb += GRP) {
    int nb = (vb + GRP < VCH) ? vb + GRP : vb;   // last iter: benign re-load
    vf4 hn[GRP];
#pragma unroll
    for (int u = 0; u < GRP; ++u)
      hn[u] = __builtin_nontemporal_load((const vf4*)(hp + (size_t)(nb + u) * NE));

#pragma unroll
    for (int u = 0; u < GRP; ++u) {
      const float4* __restrict__ r = (const float4*)(lp + (size_t)(vb + u) * 32);
      vf4 h = hc[u];
      dg.x += h.x; dg.y += h.y; dg.z += h.z; dg.w += h.w;
      {
        float4 s0 = r[0], s1 = r[1], s2 = r[2], s3 = r[3];
        float sv[16] = {s0.x,s0.y,s0.z,s0.w, s1.x,s1.y,s1.z,s1.w,
                        s2.x,s2.y,s2.z,s2.w, s3.x,s3.y,s3.z,s3.w};
#pragma unroll
        for (int k = 0; k < 16; ++k) {
          aS[k].x = fmaf(h.x, sv[k], aS[k].x);
          aS[k].y = fmaf(h.y, sv[k], aS[k].y);
          aS[k].z = fmaf(h.z, sv[k], aS[k].z);
          aS[k].w = fmaf(h.w, sv[k], aS[k].w);
        }
      }
      {
        float4 t0 = r[4], t1 = r[5], t2 = r[6], t3 = r[7];
        float tv[16] = {t0.x,t0.y,t0.z,t0.w, t1.x,t1.y,t1.z,t1.w,
                        t2.x,t2.y,t2.z,t2.w, t3.x,t3.y,t3.z,t3.w};
#pragma unroll
        for (int k = 0; k < 16; ++k) {
          aT[k].x = fmaf(h.x, tv[k], aT[k].x);
          aT[k].y = fmaf(h.y, tv[k], aT[k].y);
          aT[k].z = fmaf(h.z, tv[k], aT[k].z);
          aT[k].w = fmaf(h.w, tv[k], aT[k].w);
        }
      }
    }
#pragma unroll
    for (int u = 0; u < GRP; ++u) hc[u] = hn[u];
  }

  float* op = part + (size_t)y * 33 * NLANE + e0;
#pragma unroll
  for (int k = 0; k < 16; ++k) {
    vf4 w = {aS[k].x, aS[k].y, aS[k].z, aS[k].w};
    *(vf4*)(op + (size_t)k * NLANE) = w;
  }
#pragma unroll
  for (int k = 0; k < 16; ++k) {
    vf4 w = {aT[k].x, aT[k].y, aT[k].z, aT[k].w};
    *(vf4*)(op + (size_t)(16 + k) * NLANE) = w;
  }
  {
    vf4 w = {dg.x, dg.y, dg.z, dg.w};
    *(vf4*)(op + (size_t)32 * NLANE) = w;
  }
}

// ---------------- finale: fused y-reduction + per-edge KL + masked mean.
// Block b handles edges [b*64, b*64+64). 16 waves; wave yq accumulates
// y = yq, yq+16, ... (all 33 channels, coalesced 256B per load), LDS-combine,
// wave 0 computes KL, atomics + ticket: last block writes out.
__global__ __launch_bounds__(1024) void finale_kernel(
    const float* __restrict__ part, const unsigned char* __restrict__ e_mask,
    float* __restrict__ scal, float* __restrict__ out) {
  __shared__ float sl[33 * 64];
  int t = threadIdx.x;
  int el = t & 63, yq = t >> 6;          // wave index == yq (0..15)
  int e = blockIdx.x * 64 + el;

  float a[33];
#pragma unroll
  for (int k = 0; k < 33; ++k) a[k] = 0.f;
  for (int y = yq; y < NCH; y += 16) {
    const float* __restrict__ bp = part + (size_t)y * 33 * NLANE + e;
#pragma unroll
    for (int k = 0; k < 33; ++k) a[k] += bp[(size_t)k * NLANE];
  }

  for (int i = t; i < 33 * 64; i += 1024) sl[i] = 0.f;
  __syncthreads();
#pragma unroll
  for (int k = 0; k < 33; ++k) atomicAdd(&sl[k * 64 + el], a[k]);
  __syncthreads();

  if (t < 64) {   // wave 0: one edge per lane
    float num = 0.f, cntv = 0.f;
    if (e < NE && e_mask[e]) {
      float deg = sl[32 * 64 + el];
      float invd = 1.f / deg;
      float kl = 0.f;
#pragma unroll
      for (int k = 0; k < 16; ++k) {
        float ms = sl[k * 64 + el] * invd;
        float mt = sl[(16 + k) * 64 + el] * invd;
        float xs = ms * TAU_INV + EPS;
        float xt = mt * TAU_INV + EPS;
        kl += xt * (logf(xt) - logf(xs));
      }
      num = kl; cntv = 1.f;
    }
#pragma unroll
    for (int off = 32; off > 0; off >>= 1) {
      num += __shfl_down(num, off, 64);
      cntv += __shfl_down(cntv, off, 64);
    }
    if (t == 0) {
      atomicAdd(&scal[0], num);
      atomicAdd(&scal[1], cntv);
      __threadfence();
      unsigned int tk = atomicAdd((unsigned int*)&scal[2], 1u);
      if (tk == FB - 1) {
        float n = atomicAdd(&scal[0], 0.f);   // atomic read at coherent point
        float c = atomicAdd(&scal[1], 0.f);
        out[0] = n / fmaxf(c, 1.f);
      }
    }
  }
}

extern "C" void kernel_launch(void* const* d_in, const int* in_sizes, int n_in,
                              void* d_out, int out_size, void* d_ws, size_t ws_size,
                              hipStream_t stream) {
  const float* pred_s = (const float*)d_in[0];
  const float* pred_t = (const float*)d_in[1];
  const float* H      = (const float*)d_in[2];
  const unsigned char* e_mask = (const unsigned char*)d_in[3];

  float* ws   = (float*)d_ws;
  float* p    = ws;                                    // NV*32         (6.40 MB)
  float* part = p + (size_t)NV * 32;                   // NCH*33*NLANE  (67.6 MB)
  float* scal = part + (size_t)NCH * 33 * NLANE;       // 3 floats (num, cnt, ticket)

  softmax_kernel<<<dim3((2 * NV + 255) / 256), 256, 0, stream>>>(pred_s, pred_t, p, scal);
  accum_kernel<<<dim3(NBLK), 256, 0, stream>>>(H, p, part);
  finale_kernel<<<dim3(FB), 1024, 0, stream>>>(part, e_mask, scal, (float*)d_out);
}